// Round 1
// baseline (9134.671 us; speedup 1.0000x reference)
//
#include <hip/hip_runtime.h>
#include <hip/hip_bf16.h>

#define HDIM 512
#define BATCH 16
#define TSEQ 600
#define NROW (BATCH*TSEQ)

typedef unsigned short u16;
typedef __attribute__((ext_vector_type(8))) short short8;   // 8 x bf16 (MFMA A/B frag)
typedef __attribute__((ext_vector_type(4))) float f32x4;    // MFMA C/D frag

__device__ __forceinline__ u16 f2b(float f){
  unsigned x; __builtin_memcpy(&x, &f, 4);
  x += 0x7fffu + ((x >> 16) & 1u);            // RNE
  return (u16)(x >> 16);
}
__device__ __forceinline__ float b2f(u16 u){
  unsigned x = ((unsigned)u) << 16; float f; __builtin_memcpy(&f, &x, 4); return f;
}
__device__ __forceinline__ float sigmoidf_fast(float x){ return 1.f/(1.f+__expf(-x)); }
__device__ __forceinline__ float tanhf_fast(float x){ return 1.f - 2.f/(__expf(2.f*x)+1.f); }

// ---------------- elementwise fp32 -> bf16 ----------------
__global__ void cvt_kernel(const float* __restrict__ in, u16* __restrict__ out, int n4){
  int i = blockIdx.x*blockDim.x + threadIdx.x;
  if (i < n4){
    float4 v = ((const float4*)in)[i];
    ushort4 u; u.x=f2b(v.x); u.y=f2b(v.y); u.z=f2b(v.z); u.w=f2b(v.w);
    ((ushort4*)out)[i] = u;
  }
}

// ---------------- x [16][512][600] fp32 -> xt [b*600+t][512] bf16 ----------------
__global__ __launch_bounds__(256) void transpose_kernel(const float* __restrict__ x, u16* __restrict__ xt){
  __shared__ float tile[32][33];
  int t0 = blockIdx.x*32, h0 = blockIdx.y*32, b = blockIdx.z;
  int li = threadIdx.x & 31, lj = threadIdx.x >> 5;
  for (int j=lj; j<32; j+=8){
    int t = t0 + li;
    tile[j][li] = (t < TSEQ) ? x[((size_t)b*HDIM + h0 + j)*TSEQ + t] : 0.f;
  }
  __syncthreads();
  for (int j=lj; j<32; j+=8){
    int t = t0 + j;
    if (t < TSEQ) xt[((size_t)b*TSEQ + t)*HDIM + h0 + li] = f2b(tile[li][j]);
  }
}

// ---------------- NT GEMM: C[M,N] = A[M,K] * B[N,K]^T + bias, bf16 in, OT out ----------------
template<typename OT>
__global__ __launch_bounds__(256) void gemm_bt(const u16* __restrict__ A, const u16* __restrict__ B,
    const float* __restrict__ bias, OT* __restrict__ C, int M, int N, int K)
{
  __shared__ u16 As[128][40];   // +8 pad -> b128 reads at the 8-cycle optimum
  __shared__ u16 Bs[128][40];
  const int m0 = blockIdx.x*128, n0 = blockIdx.y*128;
  const int tid = threadIdx.x, lane = tid & 63;
  const int wr = ((tid>>6)&1)*64, wc = ((tid>>6)>>1)*64;
  const int srow = tid>>2, scol = (tid&3)*8;
  f32x4 acc[4][4] = {};
  for (int k0=0; k0<K; k0+=32){
    uint4 a0 = *(const uint4*)(A + (size_t)(m0+srow)*K    + k0 + scol);
    uint4 a1 = *(const uint4*)(A + (size_t)(m0+srow+64)*K + k0 + scol);
    uint4 b0 = *(const uint4*)(B + (size_t)(n0+srow)*K    + k0 + scol);
    uint4 b1 = *(const uint4*)(B + (size_t)(n0+srow+64)*K + k0 + scol);
    __syncthreads();
    *(uint4*)&As[srow][scol]    = a0;
    *(uint4*)&As[srow+64][scol] = a1;
    *(uint4*)&Bs[srow][scol]    = b0;
    *(uint4*)&Bs[srow+64][scol] = b1;
    __syncthreads();
    short8 af[4], bfr[4];
#pragma unroll
    for (int i=0;i<4;i++) af[i]  = *(const short8*)&As[wr + i*16 + (lane&15)][(lane>>4)*8];
#pragma unroll
    for (int i=0;i<4;i++) bfr[i] = *(const short8*)&Bs[wc + i*16 + (lane&15)][(lane>>4)*8];
#pragma unroll
    for (int i=0;i<4;i++)
#pragma unroll
      for (int j=0;j<4;j++)
        acc[i][j] = __builtin_amdgcn_mfma_f32_16x16x32_bf16(af[i], bfr[j], acc[i][j], 0,0,0);
  }
#pragma unroll
  for (int i=0;i<4;i++)
#pragma unroll
    for (int j=0;j<4;j++){
      int row = m0 + wr + i*16 + (lane>>4)*4;
      int col = n0 + wc + j*16 + (lane&15);
      float bv = bias ? bias[col] : 0.f;
#pragma unroll
      for (int r=0;r<4;r++){
        float v = acc[i][j][r] + bv;
        if (sizeof(OT) == 2) C[(size_t)(row+r)*N + col] = (OT)f2b(v);
        else                 C[(size_t)(row+r)*N + col] = (OT)v;
      }
    }
}

// ---------------- persistent bidirectional LSTM recurrence ----------------
// 32 WGs: 0..15 fwd, 16..31 bwd. WG owns 32 h-positions (all 4 gates).
// Wave wv = gate index; w_hh slice lives in VGPRs as MFMA B-frags.
#define REC_NWG 32
__global__ __launch_bounds__(256,1) void lstm_rec(
    const u16* __restrict__ xp_f, const u16* __restrict__ xp_b,   // [NROW][2048] bf16
    const float* __restrict__ whh_f, const float* __restrict__ whh_b, // [2048][512] fp32
    u16* __restrict__ h_out,  // [NROW][1024] bf16 (fwd: cols 0..511, bwd: 512..1023)
    u16* __restrict__ h_buf,  // [2 dir][2 par][16][512] bf16, par0 pre-zeroed
    unsigned* __restrict__ bar) // [0]=counter, [1]=generation, pre-zeroed
{
  __shared__ u16 h_lds[16][520];
  __shared__ float gate_lds[4][16][32];
  __shared__ float c_lds[16][32];

  const int wg  = blockIdx.x;
  const int dir = wg >> 4;
  const int P0  = (wg & 15) * 32;
  const int tid = threadIdx.x;
  const int lane = tid & 63;
  const int wv  = tid >> 6;             // gate: 0=i 1=f 2=g 3=o
  const int l15 = lane & 15, lq = lane >> 4;
  const u16* xp = dir ? xp_b : xp_f;
  const float* whh = dir ? whh_b : whh_f;
  u16* hb = h_buf + (size_t)dir * (2*16*512);

  // preload w_hh slice into registers as bf16 B-frags: breg[k-iter][col-tile]
  short8 breg[16][2];
#pragma unroll
  for (int k=0;k<16;k++)
#pragma unroll
    for (int ct=0;ct<2;ct++){
      const float* wp = whh + (size_t)(wv*512 + P0 + ct*16 + l15)*512 + k*32 + lq*8;
      float4 f0 = *(const float4*)wp;
      float4 f1 = *(const float4*)(wp+4);
      short8 bvv;
      bvv[0]=(short)f2b(f0.x); bvv[1]=(short)f2b(f0.y); bvv[2]=(short)f2b(f0.z); bvv[3]=(short)f2b(f0.w);
      bvv[4]=(short)f2b(f1.x); bvv[5]=(short)f2b(f1.y); bvv[6]=(short)f2b(f1.z); bvv[7]=(short)f2b(f1.w);
      breg[k][ct] = bvv;
    }
  for (int i=tid; i<512; i+=256) ((float*)c_lds)[i] = 0.f;
  __syncthreads();

  const int t0 = dir ? (TSEQ-1) : 0, tstep = dir ? -1 : 1;
  float xpv[2][4];
  auto load_xp = [&](int t, float out[2][4]){
#pragma unroll
    for (int ct=0;ct<2;ct++){
      int col = wv*512 + P0 + ct*16 + l15;
#pragma unroll
      for (int r=0;r<4;r++){
        int bb = lq*4 + r;
        out[ct][r] = b2f(xp[(size_t)(bb*TSEQ + t)*2048 + col]);
      }
    }
  };
  load_xp(t0, xpv);

  unsigned par = 0;
  for (int s=0; s<TSEQ; ++s){
    const int t = t0 + s*tstep;
    { // stage h_prev [16][512] bf16 into LDS
      const u16* hsrc = hb + (size_t)par*(16*512);
      int row = tid>>4, off = (tid&15)*32;
#pragma unroll
      for (int q=0;q<4;q++)
        *(uint4*)&h_lds[row][off + q*8] = *(const uint4*)(hsrc + row*512 + off + q*8);
    }
    __syncthreads();

    f32x4 acc0, acc1, accB0 = {}, accB1 = {};
    acc0[0]=xpv[0][0]; acc0[1]=xpv[0][1]; acc0[2]=xpv[0][2]; acc0[3]=xpv[0][3];
    acc1[0]=xpv[1][0]; acc1[1]=xpv[1][1]; acc1[2]=xpv[1][2]; acc1[3]=xpv[1][3];
#pragma unroll
    for (int k=0;k<16;k+=2){
      short8 af0 = *(const short8*)&h_lds[l15][ k   *32 + lq*8];
      short8 af1 = *(const short8*)&h_lds[l15][(k+1)*32 + lq*8];
      acc0  = __builtin_amdgcn_mfma_f32_16x16x32_bf16(af0, breg[k][0],   acc0,  0,0,0);
      acc1  = __builtin_amdgcn_mfma_f32_16x16x32_bf16(af0, breg[k][1],   acc1,  0,0,0);
      accB0 = __builtin_amdgcn_mfma_f32_16x16x32_bf16(af1, breg[k+1][0], accB0, 0,0,0);
      accB1 = __builtin_amdgcn_mfma_f32_16x16x32_bf16(af1, breg[k+1][1], accB1, 0,0,0);
    }
    if (s+1 < TSEQ) load_xp(t + tstep, xpv);   // prefetch next step's xp across the barrier

    // gates: D layout row=(lane>>4)*4+r (batch), col=lane&15 (pos)
#pragma unroll
    for (int r=0;r<4;r++){
      gate_lds[wv][lq*4+r][l15]      = acc0[r] + accB0[r];
      gate_lds[wv][lq*4+r][16 + l15] = acc1[r] + accB1[r];
    }
    __syncthreads();

    // c/h update: 512 (batch,pos) items, 2 per thread
#pragma unroll
    for (int j=0;j<2;j++){
      int idx = j*256 + tid;
      int bb = idx>>5, p = idx&31;
      float iv = sigmoidf_fast(gate_lds[0][bb][p]);
      float fv = sigmoidf_fast(gate_lds[1][bb][p]);
      float gv = tanhf_fast(gate_lds[2][bb][p]);
      float ov = sigmoidf_fast(gate_lds[3][bb][p]);
      float c  = fv*c_lds[bb][p] + iv*gv;
      c_lds[bb][p] = c;
      float h  = ov*tanhf_fast(c);
      u16 hu = f2b(h);
      hb[(size_t)(par^1)*(16*512) + bb*512 + P0 + p] = hu;
      h_out[(size_t)(bb*TSEQ + t)*1024 + dir*512 + P0 + p] = hu;
    }
    __threadfence();
    __syncthreads();
    if (tid == 0){
      unsigned old = __hip_atomic_fetch_add(&bar[0], 1u, __ATOMIC_ACQ_REL, __HIP_MEMORY_SCOPE_AGENT);
      if (old == REC_NWG-1){
        __hip_atomic_store(&bar[0], 0u, __ATOMIC_RELAXED, __HIP_MEMORY_SCOPE_AGENT);
        __hip_atomic_fetch_add(&bar[1], 1u, __ATOMIC_RELEASE, __HIP_MEMORY_SCOPE_AGENT);
      } else {
        while ((int)__hip_atomic_load(&bar[1], __ATOMIC_RELAXED, __HIP_MEMORY_SCOPE_AGENT) < (int)(s+1))
          __builtin_amdgcn_s_sleep(1);
        (void)__hip_atomic_load(&bar[1], __ATOMIC_ACQUIRE, __HIP_MEMORY_SCOPE_AGENT);
      }
    }
    __syncthreads();
    par ^= 1;
  }
}

// ---------------- fused LayerNorm + ReLU over last dim (512) ----------------
__global__ __launch_bounds__(256) void ln_relu_kernel(const float* __restrict__ in,
    const float* __restrict__ gw, const float* __restrict__ gb, float* __restrict__ out)
{
  __shared__ float rs[4], rss[4];
  const int row = blockIdx.x;
  const float* p = in + (size_t)row*HDIM;
  float v0 = p[threadIdx.x], v1 = p[threadIdx.x + 256];
  float s = v0 + v1, ss = v0*v0 + v1*v1;
  for (int off=32; off>0; off>>=1){
    s  += __shfl_down(s, off);
    ss += __shfl_down(ss, off);
  }
  if ((threadIdx.x & 63) == 0){ rs[threadIdx.x>>6] = s; rss[threadIdx.x>>6] = ss; }
  __syncthreads();
  float st  = rs[0]+rs[1]+rs[2]+rs[3];
  float sst = rss[0]+rss[1]+rss[2]+rss[3];
  float mu  = st * (1.f/HDIM);
  float var = sst * (1.f/HDIM) - mu*mu;
  float rstd = rsqrtf(var + 1e-5f);
  int c0 = threadIdx.x, c1 = threadIdx.x + 256;
  float y0 = (v0 - mu)*rstd*gw[c0] + gb[c0];
  float y1 = (v1 - mu)*rstd*gw[c1] + gb[c1];
  out[(size_t)row*HDIM + c0] = fmaxf(y0, 0.f);
  out[(size_t)row*HDIM + c1] = fmaxf(y1, 0.f);
}

extern "C" void kernel_launch(void* const* d_in, const int* in_sizes, int n_in,
                              void* d_out, int out_size, void* d_ws, size_t ws_size,
                              hipStream_t stream)
{
  const float* x        = (const float*)d_in[0];
  const float* wih_l0f  = (const float*)d_in[1];
  const float* whh_l0f  = (const float*)d_in[2];
  const float* b_l0f    = (const float*)d_in[3];
  const float* wih_l0b  = (const float*)d_in[4];
  const float* whh_l0b  = (const float*)d_in[5];
  const float* b_l0b    = (const float*)d_in[6];
  const float* wih_l1f  = (const float*)d_in[7];
  const float* whh_l1f  = (const float*)d_in[8];
  const float* b_l1f    = (const float*)d_in[9];
  const float* wih_l1b  = (const float*)d_in[10];
  const float* whh_l1b  = (const float*)d_in[11];
  const float* b_l1b    = (const float*)d_in[12];
  const float* fc_w     = (const float*)d_in[13];
  const float* fc_b     = (const float*)d_in[14];
  const float* ln_w     = (const float*)d_in[15];
  const float* ln_b     = (const float*)d_in[16];
  float* outp = (float*)d_out;

  char* base = (char*)d_ws;
  size_t off = 0;
  auto alloc = [&](size_t bytes)->char*{ char* p = base + off; off += (bytes + 255) & ~(size_t)255; return p; };

  unsigned* bar0 = (unsigned*)alloc(256);
  unsigned* bar1 = (unsigned*)alloc(256);
  u16* hbuf0 = (u16*)alloc((size_t)2*2*16*512*2);
  u16* hbuf1 = (u16*)alloc((size_t)2*2*16*512*2);
  size_t zero_bytes = off;                       // barriers + h_buf parity0 must start at 0
  u16* xt     = (u16*)alloc((size_t)NROW*512*2);
  u16* wb_l0f = (u16*)alloc((size_t)2048*512*2);
  u16* wb_l0b = (u16*)alloc((size_t)2048*512*2);
  u16* wb_l1f = (u16*)alloc((size_t)2048*1024*2);
  u16* wb_l1b = (u16*)alloc((size_t)2048*1024*2);
  u16* wb_fc  = (u16*)alloc((size_t)512*1024*2);
  u16* h0     = (u16*)alloc((size_t)NROW*1024*2);
  u16* h1     = (u16*)alloc((size_t)NROW*1024*2);
  u16* xpf    = (u16*)alloc((size_t)NROW*2048*2);
  u16* xpb    = (u16*)alloc((size_t)NROW*2048*2);
  float* fco  = (float*)alloc((size_t)NROW*512*4);
  (void)ws_size; (void)in_sizes; (void)n_in; (void)out_size;

  hipMemsetAsync(d_ws, 0, zero_bytes, stream);

  auto cvt = [&](const float* in, u16* out, int n){
    int n4 = n/4;
    cvt_kernel<<<dim3((n4+255)/256), 256, 0, stream>>>(in, out, n4);
  };
  cvt(wih_l0f, wb_l0f, 2048*512);
  cvt(wih_l0b, wb_l0b, 2048*512);
  cvt(wih_l1f, wb_l1f, 2048*1024);
  cvt(wih_l1b, wb_l1b, 2048*1024);
  cvt(fc_w,    wb_fc,  512*1024);

  transpose_kernel<<<dim3(19,16,16), 256, 0, stream>>>(x, xt);

  // layer 0: input projections then recurrence
  gemm_bt<u16><<<dim3(75,16), 256, 0, stream>>>(xt, wb_l0f, b_l0f, xpf, NROW, 2048, 512);
  gemm_bt<u16><<<dim3(75,16), 256, 0, stream>>>(xt, wb_l0b, b_l0b, xpb, NROW, 2048, 512);
  lstm_rec<<<dim3(REC_NWG), 256, 0, stream>>>(xpf, xpb, whh_l0f, whh_l0b, h0, hbuf0, bar0);

  // layer 1
  gemm_bt<u16><<<dim3(75,16), 256, 0, stream>>>(h0, wb_l1f, b_l1f, xpf, NROW, 2048, 1024);
  gemm_bt<u16><<<dim3(75,16), 256, 0, stream>>>(h0, wb_l1b, b_l1b, xpb, NROW, 2048, 1024);
  lstm_rec<<<dim3(REC_NWG), 256, 0, stream>>>(xpf, xpb, whh_l1f, whh_l1b, h1, hbuf1, bar1);

  // FC + LayerNorm + ReLU
  gemm_bt<float><<<dim3(75,4), 256, 0, stream>>>(h1, wb_fc, fc_b, fco, NROW, 512, 1024);
  ln_relu_kernel<<<dim3(NROW), 256, 0, stream>>>(fco, ln_w, ln_b, outp);
}